// Round 21
// baseline (35.862 us; speedup 1.0000x reference)
//
#include <hip/hip_runtime.h>
#include <hip/hip_bf16.h>
#include <stdint.h>

// SVR polynomial-kernel prediction:
//   out[m] = sum_n alpha[n] * (1 + x_p[m].X[n])^4 + b
// m=16384, n=8192, d=64, all fp32 in/out.
// R21: barrier-free wave-private pipelines, FIXED (vs R16):
//   1. 3 LDS buffers/wave, stage 2 chunks AHEAD, uniform vmcnt(4)
//      (R16 failed: 1-deep prefetch -> L2 latency exposed every chunk;
//       guide's 8-phase keeps 3 half-tiles in flight for this reason).
//      Wrapped dummy tail stages keep the count uniform; 3-buf WAR safe
//      by program order (reader of buf b finished 2 chunks before rewrite).
//   2. MT=4/BM=64, NSPLIT=4, grid 1024 = 4 blocks/CU @ launch_bounds(256,4)
//      -> 16 free-running waves/CU (R16 had only 8) -> waves de-phase,
//      MFMA windows tile the period (m114 overlap mechanism).
//   3. alpha staged to LDS in prologue -> loop's only VMEM is the gll16
//      (hand vmcnt count exact).
// Kept verbatim: pre-swizzled Xs + linear gll16 (rule 21), swizzled
// ds_read slot=(bh*4+g)^(r&7) (w*16%8==0), C-operand alpha
// (acc = a4 + a4*x.X), packed f32v2 epilogue (no inline asm -- R13),
// setprio around MFMA, xbf staging, sred cross-wave reduce,
// partials+finalize (no atomics -- R7).

typedef __attribute__((ext_vector_type(8))) short bf16x8;
typedef __attribute__((ext_vector_type(8))) unsigned short ushort8;
typedef __attribute__((ext_vector_type(4))) float f32x4;
typedef __attribute__((ext_vector_type(2))) float f32v2;

#define MM 16384
#define NN 8192
#define DD 64
#define NSPLIT 4           // n-splits -> partial slices
#define CHUNK 64           // n-cols per chunk
#define CPB 32             // chunks per block: 8192 / (4*64)
#define BM 64              // m-rows per block
#define MT 4               // m-tiles per wave (all 64 rows)

__device__ __forceinline__ unsigned short f2bf(float f) {
    uint32_t u = __float_as_uint(f);
    uint32_t r = (u + 0x7FFFu + ((u >> 16) & 1u)) >> 16;  // RNE
    return (unsigned short)r;
}

__device__ __forceinline__ void gll16(const void* g, void* l) {
    __builtin_amdgcn_global_load_lds(
        (const __attribute__((address_space(1))) unsigned int*)g,
        (__attribute__((address_space(3))) unsigned int*)l, 16, 0, 0);
}

// xp -> xbf linear row-major [16384][64] bf16.
// X  -> Xs swizzled: element (n,k) at shorts:
//   (n>>6)*4096 + (n&63)*64 + ((k>>3) ^ (n&7))*8 + (k&7),  prescaled by a4[n].
// alpha4f[n] = alpha[n]^(1/4).
__global__ void convert_kernel(const float* __restrict__ xp,
                               const float* __restrict__ X,
                               const float* __restrict__ alpha,
                               unsigned short* __restrict__ xbf,
                               unsigned short* __restrict__ Xs,
                               float* __restrict__ alpha4f) {
    const int xp4 = MM * DD / 4;          // 262144 float4 units
    const int xu = NN * DD / 8;           // 65536 16B units
    const int tot = xp4 + xu;
    int tid0 = blockIdx.x * blockDim.x + threadIdx.x;
    if (tid0 < NN) alpha4f[tid0] = sqrtf(sqrtf(alpha[tid0]));
    int stride = gridDim.x * blockDim.x;
    for (int i = tid0; i < tot; i += stride) {
        if (i < xp4) {
            float4 v = ((const float4*)xp)[i];
            ushort4 o;
            o.x = f2bf(v.x); o.y = f2bf(v.y); o.z = f2bf(v.z); o.w = f2bf(v.w);
            *(ushort4*)(xbf + (size_t)i * 4) = o;
        } else {
            int u = i - xp4;
            int n = u >> 3;
            int slot = u & 7;
            float a4 = sqrtf(sqrtf(alpha[n]));
            float4 va = ((const float4*)X)[n * 16 + slot * 2];
            float4 vb = ((const float4*)X)[n * 16 + slot * 2 + 1];
            ushort8 o;
            o[0] = f2bf(va.x * a4); o[1] = f2bf(va.y * a4);
            o[2] = f2bf(va.z * a4); o[3] = f2bf(va.w * a4);
            o[4] = f2bf(vb.x * a4); o[5] = f2bf(vb.y * a4);
            o[6] = f2bf(vb.z * a4); o[7] = f2bf(vb.w * a4);
            size_t dst = (size_t)(n >> 6) * 4096 + (n & 63) * 64
                       + ((slot ^ (n & 7)) * 8);
            *(ushort8*)(Xs + dst) = o;
        }
    }
}

// LDS map (33792 B):
//   [    0,24576): staging -- wave w at w*6144, buffer j at +j*2048
//   [24576,32768): alpha slice for this block (2048 floats = CPB*64)
//   [32768,33792): sred cross-wave reduce (256 floats)

__global__ __launch_bounds__(256, 4) void svr_main(
        const unsigned short* __restrict__ xbf,
        const unsigned short* __restrict__ Xs,
        const float* __restrict__ alpha4f,
        float* __restrict__ partials) {
    __shared__ char smem[33792];
    const int tid  = threadIdx.x;
    const int lane = tid & 63;
    const int w    = tid >> 6;            // wave 0..3 owns cols [w*16, w*16+16)
    const int r    = lane & 15;           // A-row-in-tile / B-col-in-tile
    const int g    = lane >> 4;           // k-slice selector
    const int mgroup = blockIdx.x >> 2;   // 0..255
    const int ns     = blockIdx.x & 3;    // 0..3
    const int chunk0 = ns * CPB;

    // A fragments: 4 m-tiles x 2 k-slices, register-resident (32 VGPR)
    bf16x8 a[MT][2];
#pragma unroll
    for (int mt = 0; mt < MT; ++mt)
#pragma unroll
        for (int ks = 0; ks < 2; ++ks)
            a[mt][ks] = *(const bf16x8*)(
                xbf + (size_t)(mgroup * BM + mt * 16 + r) * DD
                    + ks * 32 + g * 8);

    // prologue: stage alpha slice (8KB) + chunks 0 and 1 into bufs 0,1.
    // __syncthreads drains vmcnt to 0 -> hand count in loop is exact.
    {
        const char* ga = (const char*)(alpha4f + chunk0 * CHUNK)
                       + w * 2048 + lane * 16;
        char* la = smem + 24576 + w * 2048;
        gll16(ga, la);
        gll16(ga + 1024, la + 1024);
    }
#pragma unroll
    for (int j = 0; j < 2; ++j) {
        const char* gs = (const char*)Xs
            + (size_t)(chunk0 + j) * 8192 + w * 2048 + lane * 16;
        char* lb = smem + w * 6144 + j * 2048;
        gll16(gs, lb);
        gll16(gs + 1024, lb + 1024);
    }
    __syncthreads();

    f32v2 red2[MT][2];
#pragma unroll
    for (int mt = 0; mt < MT; ++mt) {
        red2[mt][0] = (f32v2){0.f, 0.f};
        red2[mt][1] = (f32v2){0.f, 0.f};
    }

    const float* alda = (const float*)(smem + 24576);

#pragma unroll 1
    for (int c = 0; c < CPB; ++c) {
        // stage chunk c+2 (wrapped dummy at tail keeps vmcnt count uniform)
        {
            const int cs = c + 2;
            const int src = (cs < CPB) ? cs : cs - CPB;
            const char* gs = (const char*)Xs
                + (size_t)(chunk0 + src) * 8192 + w * 2048 + lane * 16;
            char* lb = smem + w * 6144 + (cs % 3) * 2048;
            gll16(gs, lb);
            gll16(gs + 1024, lb + 1024);
        }
        // wait for chunk c's stage (allow c+1's 2 + c+2's 2 = 4 in flight)
        asm volatile("s_waitcnt vmcnt(4)" ::: "memory");
        __builtin_amdgcn_sched_barrier(0);
        // B fragments from wave-private swizzled buffer (2 ds_read_b128)
        const char* rowp = smem + w * 6144 + (c % 3) * 2048 + r * 128;
        bf16x8 b0 = *(const bf16x8*)(rowp + ((g ^ (r & 7)) * 16));
        bf16x8 b1 = *(const bf16x8*)(rowp + (((4 + g) ^ (r & 7)) * 16));
        // alpha^(1/4) for this lane's column, from LDS
        float av = alda[c * CHUNK + w * 16 + r];
        f32x4 cav = (f32x4){av, av, av, av};
        // MFMA cluster: acc = a4 + a4*(x.X)  (C-operand carries the init)
        f32x4 acc[MT];
        __builtin_amdgcn_s_setprio(1);
#pragma unroll
        for (int mt = 0; mt < MT; ++mt)
            acc[mt] = __builtin_amdgcn_mfma_f32_16x16x32_bf16(
                a[mt][0], b0, cav, 0, 0, 0);
#pragma unroll
        for (int mt = 0; mt < MT; ++mt)
            acc[mt] = __builtin_amdgcn_mfma_f32_16x16x32_bf16(
                a[mt][1], b1, acc[mt], 0, 0, 0);
        __builtin_amdgcn_s_setprio(0);
        // packed epilogue (compiler v_pk_*): red += (t*t)*(t*t)
#pragma unroll
        for (int mt = 0; mt < MT; ++mt) {
            f32v2 lo = (f32v2){acc[mt][0], acc[mt][1]};
            f32v2 hi = (f32v2){acc[mt][2], acc[mt][3]};
            f32v2 lo2 = lo * lo;
            f32v2 hi2 = hi * hi;
            red2[mt][0] = lo2 * lo2 + red2[mt][0];
            red2[mt][1] = hi2 * hi2 + red2[mt][1];
        }
    }

    // 1) shuffle-reduce across the 16 column-lanes (r) within each wave
    // 2) cross-wave combine: all 4 waves cover the SAME 64 rows
    float* sred = (float*)(smem + 32768);
#pragma unroll
    for (int mt = 0; mt < MT; ++mt)
#pragma unroll
        for (int i = 0; i < 4; ++i) {
            float v = red2[mt][i >> 1][i & 1];
            v += __shfl_xor(v, 1);
            v += __shfl_xor(v, 2);
            v += __shfl_xor(v, 4);
            v += __shfl_xor(v, 8);
            if (r == 0) sred[w * BM + mt * 16 + g * 4 + i] = v;
        }
    __syncthreads();
    if (tid < BM) {
        float s = sred[tid] + sred[BM + tid] + sred[2 * BM + tid]
                + sred[3 * BM + tid];
        partials[(size_t)ns * MM + mgroup * BM + tid] = s;
    }
}

__global__ void finalize_kernel(const float* __restrict__ partials,
                                const float* __restrict__ bbias,
                                float* __restrict__ out) {
    int m = blockIdx.x * blockDim.x + threadIdx.x;
    if (m < MM) {
        float s = bbias[0];
#pragma unroll
        for (int c = 0; c < NSPLIT; ++c) s += partials[(size_t)c * MM + m];
        out[m] = s;
    }
}

extern "C" void kernel_launch(void* const* d_in, const int* in_sizes, int n_in,
                              void* d_out, int out_size, void* d_ws, size_t ws_size,
                              hipStream_t stream) {
    const float* xp    = (const float*)d_in[0];
    const float* X     = (const float*)d_in[1];
    const float* alpha = (const float*)d_in[2];
    const float* b     = (const float*)d_in[3];
    float* out = (float*)d_out;

    // ws: xbf 2MB | Xs 1MB | alpha4f 32KB | partials 4*16384*4 = 256KB
    unsigned short* xbf = (unsigned short*)d_ws;
    unsigned short* Xs  = xbf + (size_t)MM * DD;
    float* alpha4f = (float*)(Xs + (size_t)NN * DD);
    float* partials = alpha4f + NN;

    hipLaunchKernelGGL(convert_kernel, dim3(1280), dim3(256), 0, stream,
                       xp, X, alpha, xbf, Xs, alpha4f);

    hipLaunchKernelGGL(svr_main, dim3((MM / BM) * NSPLIT), dim3(256), 0, stream,
                       xbf, Xs, alpha4f, partials);

    hipLaunchKernelGGL(finalize_kernel, dim3(MM / 256), dim3(256), 0, stream,
                       partials, b, out);
}

// Round 22
// 31.754 us; speedup vs baseline: 1.1293x; 1.1293x over previous
//
#include <hip/hip_runtime.h>
#include <hip/hip_bf16.h>
#include <stdint.h>

// SVR polynomial-kernel prediction:
//   out[m] = sum_n alpha[n] * (1 + x_p[m].X[n])^4 + b
// m=16384, n=8192, d=64, all fp32 in/out.
// FINAL = R18 (measured best, 31.86us; R20's counted-vmcnt tied at 31.88).
// Structure: BM=256, wave owns 64 rows (MT=4) x all 4 n-tiles => 32 MFMA
// per wave-chunk (MFMA:other 2.3:1 -- the one lever that moved the
// plateau, R18). Grid 512 = 2 blocks/CU at launch_bounds(256,2).
// Proven pieces: pre-swizzled Xs + linear global_load_lds (rule 21),
// swizzled ds_read slot=(bh*4+g)^(rr&7) (conflict-free), C-operand alpha
// (acc = a4 + a4*x.X, no C-init movs), packed f32v2 epilogue (compiler
// v_pk_*, no inline asm -- R13 lesson), s_setprio around MFMA cluster
// (T5), alpha prefetched one chunk ahead, partials+finalize (no atomics
// -- R7 lesson: 64 same-address RMWs/output was an 80us disaster).
// Ceiling note: 14 structure variants pin svr_main at ~25-26us =
// serialized {MFMA 8.3 + VALU-epilogue 6.8 + LDS 4 + staging 2}us,
// matching m233's 2-phase structural ratio (~30% of MFMA-only) for
// plain-HIP loops of this class. K=64-total + nonlinear per-n-tile
// epilogue blocks the 8-phase deep-K co-design; bf16 is the accuracy
// floor dtype (4.8x margin; fp8/int8 project to fail).

typedef __attribute__((ext_vector_type(8))) short bf16x8;
typedef __attribute__((ext_vector_type(8))) unsigned short ushort8;
typedef __attribute__((ext_vector_type(4))) float f32x4;
typedef __attribute__((ext_vector_type(2))) float f32v2;

#define MM 16384
#define NN 8192
#define DD 64
#define NSPLIT 8           // n-splits -> partial slices
#define CHUNK 64           // n-cols per LDS chunk
#define CHUNKS_PER_BLK 16  // 8192 / (8*64)
#define BM 256             // m-rows per block
#define MT 4               // m-tiles per wave (64 rows)

__device__ __forceinline__ unsigned short f2bf(float f) {
    uint32_t u = __float_as_uint(f);
    uint32_t r = (u + 0x7FFFu + ((u >> 16) & 1u)) >> 16;  // RNE
    return (unsigned short)r;
}

__device__ __forceinline__ void gll16(const void* g, void* l) {
    __builtin_amdgcn_global_load_lds(
        (const __attribute__((address_space(1))) unsigned int*)g,
        (__attribute__((address_space(3))) unsigned int*)l, 16, 0, 0);
}

// xp -> xbf linear row-major [16384][64] bf16.
// X  -> Xs swizzled: element (n,k) at shorts:
//   (n>>6)*4096 + (n&63)*64 + ((k>>3) ^ (n&7))*8 + (k&7),  prescaled by a4[n].
// alpha4f[n] = alpha[n]^(1/4).
__global__ void convert_kernel(const float* __restrict__ xp,
                               const float* __restrict__ X,
                               const float* __restrict__ alpha,
                               unsigned short* __restrict__ xbf,
                               unsigned short* __restrict__ Xs,
                               float* __restrict__ alpha4f) {
    const int xp4 = MM * DD / 4;          // 262144 float4 units
    const int xu = NN * DD / 8;           // 65536 16B units
    const int tot = xp4 + xu;
    int tid0 = blockIdx.x * blockDim.x + threadIdx.x;
    if (tid0 < NN) alpha4f[tid0] = sqrtf(sqrtf(alpha[tid0]));
    int stride = gridDim.x * blockDim.x;
    for (int i = tid0; i < tot; i += stride) {
        if (i < xp4) {
            float4 v = ((const float4*)xp)[i];
            ushort4 o;
            o.x = f2bf(v.x); o.y = f2bf(v.y); o.z = f2bf(v.z); o.w = f2bf(v.w);
            *(ushort4*)(xbf + (size_t)i * 4) = o;
        } else {
            int u = i - xp4;
            int n = u >> 3;
            int slot = u & 7;
            float a4 = sqrtf(sqrtf(alpha[n]));
            float4 va = ((const float4*)X)[n * 16 + slot * 2];
            float4 vb = ((const float4*)X)[n * 16 + slot * 2 + 1];
            ushort8 o;
            o[0] = f2bf(va.x * a4); o[1] = f2bf(va.y * a4);
            o[2] = f2bf(va.z * a4); o[3] = f2bf(va.w * a4);
            o[4] = f2bf(vb.x * a4); o[5] = f2bf(vb.y * a4);
            o[6] = f2bf(vb.z * a4); o[7] = f2bf(vb.w * a4);
            size_t dst = (size_t)(n >> 6) * 4096 + (n & 63) * 64
                       + ((slot ^ (n & 7)) * 8);
            *(ushort8*)(Xs + dst) = o;
        }
    }
}

__global__ __launch_bounds__(256, 2) void svr_main(
        const unsigned short* __restrict__ xbf,
        const unsigned short* __restrict__ Xs,
        const float* __restrict__ alpha4f,
        float* __restrict__ partials) {
    __shared__ char smem[16384];          // 2 x 8KB chunk buffers
    const int tid  = threadIdx.x;
    const int lane = tid & 63;
    const int w    = tid >> 6;            // wave 0..3, owns rows [w*64, w*64+64)
    const int r    = lane & 15;           // row-in-tile / col-in-tile
    const int g    = lane >> 4;           // k-slice selector
    const int mgroup = blockIdx.x >> 3;   // 0..63
    const int ns     = blockIdx.x & 7;    // 0..7

    // A fragments: 4 m-tiles x 2 k-slices, regs for whole kernel (32 VGPR)
    bf16x8 a[MT][2];
#pragma unroll
    for (int mt = 0; mt < MT; ++mt)
#pragma unroll
        for (int ks = 0; ks < 2; ++ks)
            a[mt][ks] = *(const bf16x8*)(
                xbf + (size_t)(mgroup * BM + w * 64 + mt * 16 + r) * DD
                    + ks * 32 + g * 8);

    // red accumulators as packed float2 pairs: [mt][0]=elems 0,1  [1]=2,3
    f32v2 red2[MT][2];
#pragma unroll
    for (int mt = 0; mt < MT; ++mt) {
        red2[mt][0] = (f32v2){0.f, 0.f};
        red2[mt][1] = (f32v2){0.f, 0.f};
    }

    const int chunk0 = ns * CHUNKS_PER_BLK;

    // prologue: stage chunk0 into buf0; load alpha for chunk0
    {
        const char* gs = (const char*)Xs + (size_t)chunk0 * 8192 + tid * 16;
        char* lb = smem + w * 1024;       // wave-uniform base; +lane*16 implicit
        gll16(gs, lb);
        gll16(gs + 4096, lb + 4096);
    }
    float av4[4];
#pragma unroll
    for (int nt = 0; nt < 4; ++nt)
        av4[nt] = alpha4f[chunk0 * CHUNK + nt * 16 + r];
    __syncthreads();

    int cur = 0;
#pragma unroll 1
    for (int c = 0; c < CHUNKS_PER_BLK; ++c) {
        float av4n[4];
        if (c + 1 < CHUNKS_PER_BLK) {      // stage next chunk into other buffer
            const char* gs = (const char*)Xs
                           + (size_t)(chunk0 + c + 1) * 8192 + tid * 16;
            char* lb = smem + (cur ^ 1) * 8192 + w * 1024;
            gll16(gs, lb);
            gll16(gs + 4096, lb + 4096);
#pragma unroll
            for (int nt = 0; nt < 4; ++nt)
                av4n[nt] = alpha4f[(chunk0 + c + 1) * CHUNK + nt * 16 + r];
        }
        // B fragments from swizzled LDS: rr = nt*16+r, slot = (bh*4+g)^(rr&7)
        bf16x8 b[4][2];
#pragma unroll
        for (int nt = 0; nt < 4; ++nt) {
            const int rr = nt * 16 + r;
            const char* rowp = smem + cur * 8192 + rr * 128;
#pragma unroll
            for (int bh = 0; bh < 2; ++bh) {
                const int slot = (bh * 4 + g) ^ (rr & 7);
                b[nt][bh] = *(const bf16x8*)(rowp + slot * 16);
            }
        }
        // C-operand quads: cav[nt] = {a4,a4,a4,a4} (MFMA C-input IS the init)
        f32x4 cav[4];
#pragma unroll
        for (int nt = 0; nt < 4; ++nt)
            cav[nt] = (f32x4){av4[nt], av4[nt], av4[nt], av4[nt]};
        // MFMA cluster under raised priority (T5): 32 back-to-back,
        // 16 independent chains. acc = a4 + a4*(x.X)
        f32x4 acc[MT][4];
        __builtin_amdgcn_s_setprio(1);
#pragma unroll
        for (int nt = 0; nt < 4; ++nt)
#pragma unroll
            for (int mt = 0; mt < MT; ++mt)
                acc[mt][nt] = __builtin_amdgcn_mfma_f32_16x16x32_bf16(
                    a[mt][0], b[nt][0], cav[nt], 0, 0, 0);
#pragma unroll
        for (int nt = 0; nt < 4; ++nt)
#pragma unroll
            for (int mt = 0; mt < MT; ++mt)
                acc[mt][nt] = __builtin_amdgcn_mfma_f32_16x16x32_bf16(
                    a[mt][1], b[nt][1], acc[mt][nt], 0, 0, 0);
        __builtin_amdgcn_s_setprio(0);
        // packed epilogue (compiler-generated v_pk_*): red += (t*t)*(t*t)
#pragma unroll
        for (int mt = 0; mt < MT; ++mt)
#pragma unroll
            for (int nt = 0; nt < 4; ++nt) {
                f32v2 lo = (f32v2){acc[mt][nt][0], acc[mt][nt][1]};
                f32v2 hi = (f32v2){acc[mt][nt][2], acc[mt][nt][3]};
                f32v2 lo2 = lo * lo;
                f32v2 hi2 = hi * hi;
                red2[mt][0] = lo2 * lo2 + red2[mt][0];
                red2[mt][1] = hi2 * hi2 + red2[mt][1];
            }
        __syncthreads();
        cur ^= 1;
        if (c + 1 < CHUNKS_PER_BLK) {
#pragma unroll
            for (int nt = 0; nt < 4; ++nt) av4[nt] = av4n[nt];
        }
    }

    // reduce across the 16 column-lanes (r); rows live at g*4+i per m-tile
#pragma unroll
    for (int mt = 0; mt < MT; ++mt)
#pragma unroll
        for (int i = 0; i < 4; ++i) {
            float v = red2[mt][i >> 1][i & 1];
            v += __shfl_xor(v, 1);
            v += __shfl_xor(v, 2);
            v += __shfl_xor(v, 4);
            v += __shfl_xor(v, 8);
            if (r == 0) {
                int row = mgroup * BM + w * 64 + mt * 16 + g * 4 + i;
                partials[(size_t)ns * MM + row] = v;
            }
        }
}

__global__ void finalize_kernel(const float* __restrict__ partials,
                                const float* __restrict__ bbias,
                                float* __restrict__ out) {
    int m = blockIdx.x * blockDim.x + threadIdx.x;
    if (m < MM) {
        float s = bbias[0];
#pragma unroll
        for (int c = 0; c < NSPLIT; ++c) s += partials[(size_t)c * MM + m];
        out[m] = s;
    }
}

extern "C" void kernel_launch(void* const* d_in, const int* in_sizes, int n_in,
                              void* d_out, int out_size, void* d_ws, size_t ws_size,
                              hipStream_t stream) {
    const float* xp    = (const float*)d_in[0];
    const float* X     = (const float*)d_in[1];
    const float* alpha = (const float*)d_in[2];
    const float* b     = (const float*)d_in[3];
    float* out = (float*)d_out;

    // ws: xbf 2MB | Xs 1MB | alpha4f 32KB | partials 8*16384*4 = 512KB
    unsigned short* xbf = (unsigned short*)d_ws;
    unsigned short* Xs  = xbf + (size_t)MM * DD;
    float* alpha4f = (float*)(Xs + (size_t)NN * DD);
    float* partials = alpha4f + NN;

    hipLaunchKernelGGL(convert_kernel, dim3(1280), dim3(256), 0, stream,
                       xp, X, alpha, xbf, Xs, alpha4f);

    hipLaunchKernelGGL(svr_main, dim3((MM / BM) * NSPLIT), dim3(256), 0, stream,
                       xbf, Xs, alpha4f, partials);

    hipLaunchKernelGGL(finalize_kernel, dim3(MM / 256), dim3(256), 0, stream,
                       partials, b, out);
}